// Round 7
// baseline (108.485 us; speedup 1.0000x reference)
//
#include <hip/hip_runtime.h>
#include <math.h>

#define NN 8000
#define NE 80000
#define NP 6
#define NR 6
#define NA 20
#define NC 9
#define PAC (NP*NA*NC)   // 1080
#define CUT 5.5f
#define EPSV 1e-9f
#define EB 16            // edges per LDS stage in node_accum
#define EST 57           // LDS row stride (floats) for staged edge basis

__constant__ int   c_lx[NA]  = {0, 1,0,0, 2,1,1,0,0,0, 3,2,2,1,1,1,0,0,0,0};
__constant__ int   c_ly[NA]  = {0, 0,1,0, 0,1,0,2,1,0, 0,1,0,2,1,0,3,2,1,0};
__constant__ int   c_lz[NA]  = {0, 0,0,1, 0,0,1,0,1,2, 0,0,1,0,1,2,0,1,2,3};
__constant__ int   c_ls[NA]  = {0, 1,1,1, 2,2,2,2,2,2, 3,3,3,3,3,3,3,3,3,3};
__constant__ float c_pref[NA]= {1.f, 1.f,1.f,1.f, 1.f,2.f,2.f,1.f,2.f,1.f,
                                1.f,3.f,3.f,3.f,6.f,3.f,1.f,3.f,3.f,1.f};

__device__ __forceinline__ int spec_of(int z) { return z == 1 ? 0 : (z == 6 ? 1 : 2); }

// pack two f32 -> one uint of 2 bf16 (RNE); element a in low half
__device__ __forceinline__ unsigned pk2(float a, float b) {
    unsigned ua = __float_as_uint(a);
    unsigned ub = __float_as_uint(b);
    ua += 0x7FFFu + ((ua >> 16) & 1u);
    ub += 0x7FFFu + ((ub >> 16) & 1u);
    return (ua >> 16) | (ub & 0xFFFF0000u);
}
__device__ __forceinline__ float blo(unsigned u) { return __uint_as_float(u << 16); }
__device__ __forceinline__ float bhi(unsigned u) { return __uint_as_float(u & 0xFFFF0000u); }

// ---------- 1. CSR build: LDS histogram + scan, one block ----------
__global__ __launch_bounds__(1024) void csr_build(const int* __restrict__ ei,
                                                  int* __restrict__ off, int* __restrict__ cur)
{
    __shared__ int hist[NN];       // 32 KB
    __shared__ int wsum[16];
    const int t = threadIdx.x;
    for (int i = t; i < NN; i += 1024) hist[i] = 0;
    __syncthreads();
    for (int i = t; i < NE; i += 1024) atomicAdd(&hist[ei[NE + i]], 1);
    __syncthreads();

    const int base = t * 8;
    int v[8]; int sum = 0;
    #pragma unroll
    for (int j = 0; j < 8; ++j) {
        v[j] = (base + j < NN) ? hist[base + j] : 0;
        sum += v[j];
    }
    const int lane = t & 63, w = t >> 6;   // 16 waves
    int x = sum;
    #pragma unroll
    for (int d = 1; d < 64; d <<= 1) {
        int y = __shfl_up(x, d);
        if (lane >= d) x += y;
    }
    if (lane == 63) wsum[w] = x;
    __syncthreads();
    if (t < 64) {
        int y = (t < 16) ? wsum[t] : 0;
        #pragma unroll
        for (int d = 1; d < 16; d <<= 1) {
            int z = __shfl_up(y, d);
            if (lane >= d) y += z;
        }
        if (t < 16) wsum[t] = y;
    }
    __syncthreads();
    int excl = ((w > 0) ? wsum[w - 1] : 0) + (x - sum);
    #pragma unroll
    for (int j = 0; j < 8; ++j) {
        if (base + j < NN) { off[base + j] = excl; cur[base + j] = excl; }
        excl += v[j];
    }
    if (t == 0) off[NN] = NE;
}

// ---------- 2. CSR fill: edge id + sender per slot ----------
__global__ __launch_bounds__(256) void csr_fill(
    const int* __restrict__ ei, int* __restrict__ cur,
    int* __restrict__ elist, int* __restrict__ slist)
{
    const int e = blockIdx.x * blockDim.x + threadIdx.x;
    if (e >= NE) return;
    const int pos = atomicAdd(&cur[ei[NE + e]], 1);
    elist[pos] = e;
    slist[pos] = ei[e];
}

// ---------- 3. node-centric: fused per-edge basis + accumulation -> bf16 A0 ----------
__global__ __launch_bounds__(128) void node_accum(
    const float* __restrict__ pos, const int* __restrict__ atnum,
    const float* __restrict__ shifts,
    const float* __restrict__ embW, const float* __restrict__ radW,
    const int* __restrict__ off, const int* __restrict__ elist,
    const int* __restrict__ slist,
    unsigned short* __restrict__ A0h, float* __restrict__ fclist)
{
    const int n = blockIdx.x;
    const int tid = threadIdx.x;
    // 120 accumulation threads: tid = p*NA + a
    const bool act = (tid < NP * NA);
    const int p = tid / NA, a = tid % NA;
    const int l = (a >= 1) + (a >= 4) + (a >= 10);
    const int iR = l*NP + p;

    float acc[NC];
    #pragma unroll
    for (int c = 0; c < NC; ++c) acc[c] = 0.f;

    __shared__ float sE[EB][EST];   // per-edge basis: Rl[0,24) ang[24,44) enc[44,53)
    __shared__ __align__(16) float sRow[PAC];

    const float rxp = pos[n*3+0], ryp = pos[n*3+1], rzp = pos[n*3+2];
    const int sr_recv = spec_of(atnum[n]);
    const float er0 = embW[sr_recv*3+0], er1 = embW[sr_recv*3+1], er2 = embW[sr_recv*3+2];

    const int st = off[n], en = off[n+1];
    for (int i0 = st; i0 < en; i0 += EB) {
        const int nb = min(EB, en - i0);
        __syncthreads();
        if (tid < nb) {
            const int slot = i0 + tid;
            const int e = elist[slot];
            const int s = slist[slot];

            const float dx = rxp - pos[s*3+0] + shifts[e*3+0];
            const float dy = ryp - pos[s*3+1] + shifts[e*3+1];
            const float dz = rzp - pos[s*3+2] + shifts[e*3+2];
            const float len = sqrtf(dx*dx + dy*dy + dz*dz);
            const float inv = 1.f / (len + EPSV);
            const float ux = dx*inv, uy = dy*inv, uz = dz*inv;

            const float u  = len / CUT;
            const float u2 = u*u;
            const float u6 = u2*u2*u2;
            const float fcut = (u < 1.f) ? (1.f - 28.f*u6 + 48.f*u6*u - 21.f*u6*u2) : 0.f;
            fclist[slot] = fcut;

            // radial: sin recurrence
            float rad[NR];
            {
                const float th = len * (float)(M_PI / (double)CUT);
                float sc, cc;
                sincosf(th, &sc, &cc);
                const float cr = sqrtf(2.f/CUT) * inv;
                const float c2 = 2.f * cc;
                float skm1 = 0.f, sk = sc;
                #pragma unroll
                for (int k = 0; k < NR; ++k) {
                    rad[k] = cr * sk;
                    const float nx = c2 * sk - skm1;
                    skm1 = sk; sk = nx;
                }
            }
            #pragma unroll
            for (int ll = 0; ll < 4; ++ll)
                #pragma unroll
                for (int pp = 0; pp < NP; ++pp) {
                    float dsum = 0.f;
                    #pragma unroll
                    for (int rr = 0; rr < NR; ++rr)
                        dsum += rad[rr] * radW[ll*NR*NP + rr*NP + pp];
                    sE[tid][ll*NP + pp] = fcut * dsum;
                }
            {
                float px[4] = {1.f, ux, ux*ux, ux*ux*ux};
                float py[4] = {1.f, uy, uy*uy, uy*uy*uy};
                float pz[4] = {1.f, uz, uz*uz, uz*uz*uz};
                #pragma unroll
                for (int aa = 0; aa < NA; ++aa)
                    sE[tid][24 + aa] = px[c_lx[aa]] * py[c_ly[aa]] * pz[c_lz[aa]];
            }
            {
                const int ss = spec_of(atnum[s]);
                const float es0 = embW[ss*3+0], es1 = embW[ss*3+1], es2 = embW[ss*3+2];
                // enc[c] = embW_send[c/3] * embW_recv[c%3]
                sE[tid][44+0] = es0*er0; sE[tid][44+1] = es0*er1; sE[tid][44+2] = es0*er2;
                sE[tid][44+3] = es1*er0; sE[tid][44+4] = es1*er1; sE[tid][44+5] = es1*er2;
                sE[tid][44+6] = es2*er0; sE[tid][44+7] = es2*er1; sE[tid][44+8] = es2*er2;
            }
        }
        __syncthreads();
        if (act) {
            for (int b = 0; b < nb; ++b) {
                const float ra = sE[b][iR] * sE[b][24 + a];
                #pragma unroll
                for (int c = 0; c < NC; ++c) acc[c] = fmaf(ra, sE[b][44 + c], acc[c]);
            }
        }
    }
    if (act) {
        #pragma unroll
        for (int c = 0; c < NC; ++c) sRow[tid * NC + c] = acc[c];
    }
    __syncthreads();

    // pack 1080 floats -> 270 uint2 chunks
    uint2* __restrict__ row = (uint2*)(A0h + (size_t)n * PAC);
    #pragma unroll
    for (int k = 0; k < 3; ++k) {
        const int q = tid + 128 * k;
        if (q < 270) {
            const float* s4 = &sRow[4 * q];
            row[q] = make_uint2(pk2(s4[0], s4[1]), pk2(s4[2], s4[3]));
        }
    }
}

// ---------- 4. fused MP gather (bf16) + symmetrize + output ----------
__global__ __launch_bounds__(256) void node_mp_final(
    const unsigned short* __restrict__ A0h,
    const int* __restrict__ slist, const float* __restrict__ fclist,
    const int* __restrict__ off, const float* __restrict__ memc,
    float* __restrict__ out)
{
    const int n = blockIdx.x;
    const int tid = threadIdx.x;

    __shared__ int   sS[256];
    __shared__ float sF[256];
    __shared__ __align__(16) float sA[2 * PAC];   // [0,1080): A0_n  [1080,2160): A1_n
    __shared__ __align__(16) float sOut[544];

    const int st = off[n], en = off[n+1];
    const int q0 = tid, q1 = tid + 256;           // uint2 chunk ids (270 total)
    float4 acc0 = {0,0,0,0}, acc1 = {0,0,0,0};

    for (int b0 = st; b0 < en; b0 += 256) {
        const int nb = min(256, en - b0);
        __syncthreads();
        if (tid < nb) { sS[tid] = slist[b0 + tid]; sF[tid] = fclist[b0 + tid]; }
        __syncthreads();
        int j = 0;
        for (; j + 8 <= nb; j += 8) {
            uint2 v[8], w[8];
            #pragma unroll
            for (int k = 0; k < 8; ++k)
                v[k] = ((const uint2*)(A0h + (size_t)sS[j+k] * PAC))[q0];
            if (tid < 14) {
                #pragma unroll
                for (int k = 0; k < 8; ++k)
                    w[k] = ((const uint2*)(A0h + (size_t)sS[j+k] * PAC))[q1];
            }
            #pragma unroll
            for (int k = 0; k < 8; ++k) {
                const float f = sF[j+k];
                acc0.x = fmaf(f, blo(v[k].x), acc0.x);
                acc0.y = fmaf(f, bhi(v[k].x), acc0.y);
                acc0.z = fmaf(f, blo(v[k].y), acc0.z);
                acc0.w = fmaf(f, bhi(v[k].y), acc0.w);
                if (tid < 14) {
                    acc1.x = fmaf(f, blo(w[k].x), acc1.x);
                    acc1.y = fmaf(f, bhi(w[k].x), acc1.y);
                    acc1.z = fmaf(f, blo(w[k].y), acc1.z);
                    acc1.w = fmaf(f, bhi(w[k].y), acc1.w);
                }
            }
        }
        for (; j < nb; ++j) {
            const float f = sF[j];
            const uint2* rh = (const uint2*)(A0h + (size_t)sS[j] * PAC);
            uint2 v = rh[q0];
            acc0.x = fmaf(f, blo(v.x), acc0.x);
            acc0.y = fmaf(f, bhi(v.x), acc0.y);
            acc0.z = fmaf(f, blo(v.y), acc0.z);
            acc0.w = fmaf(f, bhi(v.y), acc0.w);
            if (tid < 14) {
                uint2 w = rh[q1];
                acc1.x = fmaf(f, blo(w.x), acc1.x);
                acc1.y = fmaf(f, bhi(w.x), acc1.y);
                acc1.z = fmaf(f, blo(w.y), acc1.z);
                acc1.w = fmaf(f, bhi(w.y), acc1.w);
            }
        }
    }

    const float mc  = memc[0];
    const float mpn = 0.3162277660168379f;  // 1/sqrt(10)
    const uint2* __restrict__ rowN = (const uint2*)(A0h + (size_t)n * PAC);
    {
        uint2 v = rowN[q0];
        const float x0 = blo(v.x), x1 = bhi(v.x), x2 = blo(v.y), x3 = bhi(v.y);
        ((float4*)sA)[q0] = make_float4(x0, x1, x2, x3);
        ((float4*)(sA + PAC))[q0] = make_float4(
            fmaf(mc, x0, mpn * acc0.x), fmaf(mc, x1, mpn * acc0.y),
            fmaf(mc, x2, mpn * acc0.z), fmaf(mc, x3, mpn * acc0.w));
        if (tid < 14) {
            uint2 w = rowN[q1];
            const float y0 = blo(w.x), y1 = bhi(w.x), y2 = blo(w.y), y3 = bhi(w.y);
            ((float4*)sA)[q1] = make_float4(y0, y1, y2, y3);
            ((float4*)(sA + PAC))[q1] = make_float4(
                fmaf(mc, y0, mpn * acc1.x), fmaf(mc, y1, mpn * acc1.y),
                fmaf(mc, y2, mpn * acc1.z), fmaf(mc, y3, mpn * acc1.w));
        }
    }
    __syncthreads();

    if (tid < NP * NC) {
        const int p = tid / NC, c = tid % NC;
        const int base = p * (NA * NC) + c;
        float b20[4] = {0.f,0.f,0.f,0.f};
        float b21[4] = {0.f,0.f,0.f,0.f};
        #pragma unroll
        for (int a = 0; a < NA; ++a) {
            const int ll = c_ls[a];
            const float pr = c_pref[a];
            const float x0 = sA[base + a*NC];
            const float x1 = sA[PAC + base + a*NC];
            b20[ll] = fmaf(pr * x0, x0, b20[ll]);
            b21[ll] = fmaf(pr * x1, x1, b21[ll]);
        }
        const int ob = p*90 + c*2;
        sOut[ob]     = sA[base];
        sOut[ob + 1] = sA[PAC + base];
        #pragma unroll
        for (int ll = 0; ll < 4; ++ll) {
            sOut[ob + (ll+1)*18]     = b20[ll];
            sOut[ob + (ll+1)*18 + 1] = b21[ll];
        }
    }
    __syncthreads();

    float4* __restrict__ o4 = (float4*)(out + (size_t)n * 540);
    if (tid < 135) o4[tid] = ((const float4*)sOut)[tid];
}

extern "C" void kernel_launch(void* const* d_in, const int* in_sizes, int n_in,
                              void* d_out, int out_size, void* d_ws, size_t ws_size,
                              hipStream_t stream) {
    const float* pos    = (const float*)d_in[0];
    const int*   atnum  = (const int*)d_in[1];
    const int*   ei     = (const int*)d_in[2];
    const float* shifts = (const float*)d_in[3];
    const float* embW   = (const float*)d_in[4];
    const float* radW   = (const float*)d_in[5];
    const float* memc   = (const float*)d_in[6];
    float* out = (float*)d_out;

    unsigned short* A0h = (unsigned short*)d_ws;               // NN*1080 bf16 (17.28 MB)
    float* fclist = (float*)(A0h + (size_t)NN * PAC);          // NE
    int*   off    = (int*)(fclist + NE);                       // NN+1
    int*   cur    = off + NN + 1;                              // NN
    int*   elist  = cur + NN;                                  // NE
    int*   slist  = elist + NE;                                // NE

    csr_build<<<1, 1024, 0, stream>>>(ei, off, cur);
    csr_fill<<<(NE+255)/256, 256, 0, stream>>>(ei, cur, elist, slist);
    node_accum<<<NN, 128, 0, stream>>>(pos, atnum, shifts, embW, radW,
                                       off, elist, slist, A0h, fclist);
    node_mp_final<<<NN, 256, 0, stream>>>(A0h, slist, fclist, off, memc, out);
}

// Round 8
// 102.770 us; speedup vs baseline: 1.0556x; 1.0556x over previous
//
#include <hip/hip_runtime.h>
#include <math.h>

#define NN 8000
#define NE 80000
#define NP 6
#define NR 6
#define NA 20
#define NC 9
#define PAC (NP*NA*NC)   // 1080
#define EDW 28           // per-slot packed row: 56 bf16 = 28 uints (112 B)
#define CUT 5.5f
#define EPSV 1e-9f

__constant__ int   c_lx[NA]  = {0, 1,0,0, 2,1,1,0,0,0, 3,2,2,1,1,1,0,0,0,0};
__constant__ int   c_ly[NA]  = {0, 0,1,0, 0,1,0,2,1,0, 0,1,0,2,1,0,3,2,1,0};
__constant__ int   c_lz[NA]  = {0, 0,0,1, 0,0,1,0,1,2, 0,0,1,0,1,2,0,1,2,3};
__constant__ int   c_ls[NA]  = {0, 1,1,1, 2,2,2,2,2,2, 3,3,3,3,3,3,3,3,3,3};
__constant__ float c_pref[NA]= {1.f, 1.f,1.f,1.f, 1.f,2.f,2.f,1.f,2.f,1.f,
                                1.f,3.f,3.f,3.f,6.f,3.f,1.f,3.f,3.f,1.f};

__device__ __forceinline__ int spec_of(int z) { return z == 1 ? 0 : (z == 6 ? 1 : 2); }

// pack two f32 -> one uint of 2 bf16 (RNE); element a in low half
__device__ __forceinline__ unsigned pk2(float a, float b) {
    unsigned ua = __float_as_uint(a);
    unsigned ub = __float_as_uint(b);
    ua += 0x7FFFu + ((ua >> 16) & 1u);
    ub += 0x7FFFu + ((ub >> 16) & 1u);
    return (ua >> 16) | (ub & 0xFFFF0000u);
}
__device__ __forceinline__ float blo(unsigned u) { return __uint_as_float(u << 16); }
__device__ __forceinline__ float bhi(unsigned u) { return __uint_as_float(u & 0xFFFF0000u); }
// element f (bf16 element index) from packed array
__device__ __forceinline__ float bfh(const unsigned* E, int f) {
    unsigned w = E[f >> 1];
    return (f & 1) ? bhi(w) : blo(w);
}

// ---------- 1. CSR build: LDS histogram + scan, one block ----------
__global__ __launch_bounds__(1024) void csr_build(const int* __restrict__ ei,
                                                  int* __restrict__ off, int* __restrict__ cur)
{
    __shared__ int hist[NN];       // 32 KB
    __shared__ int wsum[16];
    const int t = threadIdx.x;
    for (int i = t; i < NN; i += 1024) hist[i] = 0;
    __syncthreads();
    for (int i = t; i < NE; i += 1024) atomicAdd(&hist[ei[NE + i]], 1);
    __syncthreads();

    const int base = t * 8;
    int v[8]; int sum = 0;
    #pragma unroll
    for (int j = 0; j < 8; ++j) {
        v[j] = (base + j < NN) ? hist[base + j] : 0;
        sum += v[j];
    }
    const int lane = t & 63, w = t >> 6;   // 16 waves
    int x = sum;
    #pragma unroll
    for (int d = 1; d < 64; d <<= 1) {
        int y = __shfl_up(x, d);
        if (lane >= d) x += y;
    }
    if (lane == 63) wsum[w] = x;
    __syncthreads();
    if (t < 64) {
        int y = (t < 16) ? wsum[t] : 0;
        #pragma unroll
        for (int d = 1; d < 16; d <<= 1) {
            int z = __shfl_up(y, d);
            if (lane >= d) y += z;
        }
        if (t < 16) wsum[t] = y;
    }
    __syncthreads();
    int excl = ((w > 0) ? wsum[w - 1] : 0) + (x - sum);
    #pragma unroll
    for (int j = 0; j < 8; ++j) {
        if (base + j < NN) { off[base + j] = excl; cur[base + j] = excl; }
        excl += v[j];
    }
    if (t == 0) off[NN] = NE;
}

// ---------- 2. CSR fill: per-slot edge/sender/receiver ----------
__global__ __launch_bounds__(256) void csr_fill(
    const int* __restrict__ ei, int* __restrict__ cur,
    int* __restrict__ elist, int* __restrict__ slist, int* __restrict__ rlist)
{
    const int e = blockIdx.x * blockDim.x + threadIdx.x;
    if (e >= NE) return;
    const int r = ei[NE + e];
    const int pos = atomicAdd(&cur[r], 1);
    elist[pos] = e;
    slist[pos] = ei[e];
    rlist[pos] = r;
}

// ---------- 3. per-SLOT factorized basis, packed bf16, written in CSR order ----------
__global__ __launch_bounds__(256) void edge_basis(
    const float* __restrict__ pos, const int* __restrict__ atnum,
    const float* __restrict__ shifts,
    const float* __restrict__ embW, const float* __restrict__ radW,
    const int* __restrict__ elist, const int* __restrict__ slist,
    const int* __restrict__ rlist,
    unsigned* __restrict__ edat, float* __restrict__ fclist)
{
    const int slot = blockIdx.x * blockDim.x + threadIdx.x;
    if (slot >= NE) return;
    const int e = elist[slot];
    const int s = slist[slot];
    const int r = rlist[slot];

    const float dx = pos[r*3+0] - pos[s*3+0] + shifts[e*3+0];
    const float dy = pos[r*3+1] - pos[s*3+1] + shifts[e*3+1];
    const float dz = pos[r*3+2] - pos[s*3+2] + shifts[e*3+2];
    const float len = sqrtf(dx*dx + dy*dy + dz*dz);
    const float inv = 1.f / (len + EPSV);
    const float ux = dx*inv, uy = dy*inv, uz = dz*inv;

    const float u  = len / CUT;
    const float u2 = u*u;
    const float u6 = u2*u2*u2;
    const float fcut = (u < 1.f) ? (1.f - 28.f*u6 + 48.f*u6*u - 21.f*u6*u2) : 0.f;
    fclist[slot] = fcut;

    float E[56];

    // rad[k] = sqrt(2/CUT)*sin((k+1)*pi*len/CUT)/len via sin recurrence
    float rad[NR];
    {
        const float th = len * (float)(M_PI / (double)CUT);
        float sc, cc;
        sincosf(th, &sc, &cc);
        const float cr = sqrtf(2.f/CUT) * inv;
        const float c2 = 2.f * cc;
        float skm1 = 0.f, sk = sc;
        #pragma unroll
        for (int k = 0; k < NR; ++k) {
            rad[k] = cr * sk;
            const float nx = c2 * sk - skm1;
            skm1 = sk; sk = nx;
        }
    }

    #pragma unroll
    for (int l = 0; l < 4; ++l)
        #pragma unroll
        for (int p = 0; p < NP; ++p) {
            float acc = 0.f;
            #pragma unroll
            for (int rr = 0; rr < NR; ++rr) acc += rad[rr] * radW[l*NR*NP + rr*NP + p];
            E[l*NP + p] = fcut * acc;
        }

    {
        float px[4] = {1.f, ux, ux*ux, ux*ux*ux};
        float py[4] = {1.f, uy, uy*uy, uy*uy*uy};
        float pz[4] = {1.f, uz, uz*uz, uz*uz*uz};
        #pragma unroll
        for (int a = 0; a < NA; ++a)
            E[24 + a] = px[c_lx[a]] * py[c_ly[a]] * pz[c_lz[a]];
    }
    {
        const int ss = spec_of(atnum[s]), sr = spec_of(atnum[r]);
        #pragma unroll
        for (int c = 0; c < NC; ++c)
            E[44 + c] = embW[ss*3 + c/3] * embW[sr*3 + c%3];
    }
    E[53] = 0.f; E[54] = 0.f; E[55] = 0.f;

    unsigned P[EDW];
    #pragma unroll
    for (int f = 0; f < EDW; ++f) P[f] = pk2(E[2*f], E[2*f+1]);

    uint4* __restrict__ E4 = (uint4*)(edat + (size_t)slot * EDW);
    #pragma unroll
    for (int f = 0; f < 7; ++f)
        E4[f] = make_uint4(P[4*f], P[4*f+1], P[4*f+2], P[4*f+3]);
}

// ---------- 4. node-centric A0 accumulation: CONTIGUOUS slot stream -> bf16 row ----------
#define EB 16
__global__ __launch_bounds__(128) void node_accum(
    const unsigned* __restrict__ edat, const int* __restrict__ off,
    unsigned short* __restrict__ A0h)
{
    const int n = blockIdx.x;
    const int tid = threadIdx.x;
    // 120 active threads: tid = p*NA + a
    const bool act = (tid < NP * NA);
    const int p = tid / NA, a = tid % NA;
    const int l = (a >= 1) + (a >= 4) + (a >= 10);
    const int iR = l*NP + p;

    float acc[NC];
    #pragma unroll
    for (int c = 0; c < NC; ++c) acc[c] = 0.f;

    __shared__ uint4 sE4[EB * 7];
    const unsigned* sE = (const unsigned*)sE4;
    __shared__ __align__(16) float sRow[PAC];

    const int st = off[n], en = off[n+1];
    const uint4* __restrict__ gbase = (const uint4*)(edat) ;
    for (int i0 = st; i0 < en; i0 += EB) {
        const int nb = min(EB, en - i0);
        __syncthreads();
        // contiguous coalesced stage: slots i0..i0+nb
        for (int q = tid; q < nb * 7; q += 128)
            sE4[q] = gbase[(size_t)i0 * 7 + q];
        __syncthreads();
        if (act) {
            for (int b = 0; b < nb; ++b) {
                const unsigned* E = &sE[b * EDW];
                const float ra = bfh(E, iR) * bfh(E, 24 + a);
                #pragma unroll
                for (int c = 0; c < NC; ++c) acc[c] = fmaf(ra, bfh(E, 44 + c), acc[c]);
            }
        }
    }
    if (act) {
        #pragma unroll
        for (int c = 0; c < NC; ++c) sRow[tid * NC + c] = acc[c];
    }
    __syncthreads();

    // pack 1080 floats -> 270 uint2 chunks
    uint2* __restrict__ row = (uint2*)(A0h + (size_t)n * PAC);
    #pragma unroll
    for (int k = 0; k < 3; ++k) {
        const int q = tid + 128 * k;
        if (q < 270) {
            const float* s4 = &sRow[4 * q];
            row[q] = make_uint2(pk2(s4[0], s4[1]), pk2(s4[2], s4[3]));
        }
    }
}

// ---------- 5. fused MP gather (bf16) + symmetrize + output ----------
__global__ __launch_bounds__(256) void node_mp_final(
    const unsigned short* __restrict__ A0h,
    const int* __restrict__ slist, const float* __restrict__ fclist,
    const int* __restrict__ off, const float* __restrict__ memc,
    float* __restrict__ out)
{
    const int n = blockIdx.x;
    const int tid = threadIdx.x;

    __shared__ int   sS[256];
    __shared__ float sF[256];
    __shared__ __align__(16) float sA[2 * PAC];   // [0,1080): A0_n  [1080,2160): A1_n
    __shared__ __align__(16) float sOut[544];

    const int st = off[n], en = off[n+1];
    const int q0 = tid, q1 = tid + 256;           // uint2 chunk ids (270 total)
    float4 acc0 = {0,0,0,0}, acc1 = {0,0,0,0};

    for (int b0 = st; b0 < en; b0 += 256) {
        const int nb = min(256, en - b0);
        __syncthreads();
        if (tid < nb) { sS[tid] = slist[b0 + tid]; sF[tid] = fclist[b0 + tid]; }
        __syncthreads();
        int j = 0;
        for (; j + 8 <= nb; j += 8) {
            uint2 v[8], w[8];
            #pragma unroll
            for (int k = 0; k < 8; ++k)
                v[k] = ((const uint2*)(A0h + (size_t)sS[j+k] * PAC))[q0];
            if (tid < 14) {
                #pragma unroll
                for (int k = 0; k < 8; ++k)
                    w[k] = ((const uint2*)(A0h + (size_t)sS[j+k] * PAC))[q1];
            }
            #pragma unroll
            for (int k = 0; k < 8; ++k) {
                const float f = sF[j+k];
                acc0.x = fmaf(f, blo(v[k].x), acc0.x);
                acc0.y = fmaf(f, bhi(v[k].x), acc0.y);
                acc0.z = fmaf(f, blo(v[k].y), acc0.z);
                acc0.w = fmaf(f, bhi(v[k].y), acc0.w);
                if (tid < 14) {
                    acc1.x = fmaf(f, blo(w[k].x), acc1.x);
                    acc1.y = fmaf(f, bhi(w[k].x), acc1.y);
                    acc1.z = fmaf(f, blo(w[k].y), acc1.z);
                    acc1.w = fmaf(f, bhi(w[k].y), acc1.w);
                }
            }
        }
        for (; j < nb; ++j) {
            const float f = sF[j];
            const uint2* rh = (const uint2*)(A0h + (size_t)sS[j] * PAC);
            uint2 v = rh[q0];
            acc0.x = fmaf(f, blo(v.x), acc0.x);
            acc0.y = fmaf(f, bhi(v.x), acc0.y);
            acc0.z = fmaf(f, blo(v.y), acc0.z);
            acc0.w = fmaf(f, bhi(v.y), acc0.w);
            if (tid < 14) {
                uint2 w = rh[q1];
                acc1.x = fmaf(f, blo(w.x), acc1.x);
                acc1.y = fmaf(f, bhi(w.x), acc1.y);
                acc1.z = fmaf(f, blo(w.y), acc1.z);
                acc1.w = fmaf(f, bhi(w.y), acc1.w);
            }
        }
    }

    const float mc  = memc[0];
    const float mpn = 0.3162277660168379f;  // 1/sqrt(10)
    const uint2* __restrict__ rowN = (const uint2*)(A0h + (size_t)n * PAC);
    {
        uint2 v = rowN[q0];
        const float x0 = blo(v.x), x1 = bhi(v.x), x2 = blo(v.y), x3 = bhi(v.y);
        ((float4*)sA)[q0] = make_float4(x0, x1, x2, x3);
        ((float4*)(sA + PAC))[q0] = make_float4(
            fmaf(mc, x0, mpn * acc0.x), fmaf(mc, x1, mpn * acc0.y),
            fmaf(mc, x2, mpn * acc0.z), fmaf(mc, x3, mpn * acc0.w));
        if (tid < 14) {
            uint2 w = rowN[q1];
            const float y0 = blo(w.x), y1 = bhi(w.x), y2 = blo(w.y), y3 = bhi(w.y);
            ((float4*)sA)[q1] = make_float4(y0, y1, y2, y3);
            ((float4*)(sA + PAC))[q1] = make_float4(
                fmaf(mc, y0, mpn * acc1.x), fmaf(mc, y1, mpn * acc1.y),
                fmaf(mc, y2, mpn * acc1.z), fmaf(mc, y3, mpn * acc1.w));
        }
    }
    __syncthreads();

    if (tid < NP * NC) {
        const int p = tid / NC, c = tid % NC;
        const int base = p * (NA * NC) + c;
        float b20[4] = {0.f,0.f,0.f,0.f};
        float b21[4] = {0.f,0.f,0.f,0.f};
        #pragma unroll
        for (int a = 0; a < NA; ++a) {
            const int ll = c_ls[a];
            const float pr = c_pref[a];
            const float x0 = sA[base + a*NC];
            const float x1 = sA[PAC + base + a*NC];
            b20[ll] = fmaf(pr * x0, x0, b20[ll]);
            b21[ll] = fmaf(pr * x1, x1, b21[ll]);
        }
        const int ob = p*90 + c*2;
        sOut[ob]     = sA[base];
        sOut[ob + 1] = sA[PAC + base];
        #pragma unroll
        for (int ll = 0; ll < 4; ++ll) {
            sOut[ob + (ll+1)*18]     = b20[ll];
            sOut[ob + (ll+1)*18 + 1] = b21[ll];
        }
    }
    __syncthreads();

    float4* __restrict__ o4 = (float4*)(out + (size_t)n * 540);
    if (tid < 135) o4[tid] = ((const float4*)sOut)[tid];
}

extern "C" void kernel_launch(void* const* d_in, const int* in_sizes, int n_in,
                              void* d_out, int out_size, void* d_ws, size_t ws_size,
                              hipStream_t stream) {
    const float* pos    = (const float*)d_in[0];
    const int*   atnum  = (const int*)d_in[1];
    const int*   ei     = (const int*)d_in[2];
    const float* shifts = (const float*)d_in[3];
    const float* embW   = (const float*)d_in[4];
    const float* radW   = (const float*)d_in[5];
    const float* memc   = (const float*)d_in[6];
    float* out = (float*)d_out;

    unsigned*       edat = (unsigned*)d_ws;                    // NE*28 uints (8.96 MB)
    unsigned short* A0h  = (unsigned short*)(edat + (size_t)NE * EDW);  // NN*1080 bf16 (17.28 MB)
    float* fclist = (float*)(A0h + (size_t)NN * PAC);          // NE
    int*   off    = (int*)(fclist + NE);                       // NN+1
    int*   cur    = off + NN + 1;                              // NN
    int*   elist  = cur + NN;                                  // NE
    int*   slist  = elist + NE;                                // NE
    int*   rlist  = slist + NE;                                // NE

    csr_build<<<1, 1024, 0, stream>>>(ei, off, cur);
    csr_fill<<<(NE+255)/256, 256, 0, stream>>>(ei, cur, elist, slist, rlist);
    edge_basis<<<(NE+255)/256, 256, 0, stream>>>(pos, atnum, shifts, embW, radW,
                                                 elist, slist, rlist, edat, fclist);
    node_accum<<<NN, 128, 0, stream>>>(edat, off, A0h);
    node_mp_final<<<NN, 256, 0, stream>>>(A0h, slist, fclist, off, memc, out);
}

// Round 9
// 94.597 us; speedup vs baseline: 1.1468x; 1.0864x over previous
//
#include <hip/hip_runtime.h>
#include <math.h>

#define NN 8000
#define NE 80000
#define NP 6
#define NR 6
#define NA 20
#define NC 9
#define PAC (NP*NA*NC)   // 1080
#define EDW 28           // per-slot packed row: 56 bf16 = 28 uints (112 B)
#define CUT 5.5f
#define EPSV 1e-9f
#define MPT 192          // node_mp_final block size (3 waves)
#define EB 16            // edges per LDS stage in node_accum

__constant__ int   c_lx[NA]  = {0, 1,0,0, 2,1,1,0,0,0, 3,2,2,1,1,1,0,0,0,0};
__constant__ int   c_ly[NA]  = {0, 0,1,0, 0,1,0,2,1,0, 0,1,0,2,1,0,3,2,1,0};
__constant__ int   c_lz[NA]  = {0, 0,0,1, 0,0,1,0,1,2, 0,0,1,0,1,2,0,1,2,3};
__constant__ int   c_ls[NA]  = {0, 1,1,1, 2,2,2,2,2,2, 3,3,3,3,3,3,3,3,3,3};
__constant__ float c_pref[NA]= {1.f, 1.f,1.f,1.f, 1.f,2.f,2.f,1.f,2.f,1.f,
                                1.f,3.f,3.f,3.f,6.f,3.f,1.f,3.f,3.f,1.f};

__device__ __forceinline__ int spec_of(int z) { return z == 1 ? 0 : (z == 6 ? 1 : 2); }

// pack two f32 -> one uint of 2 bf16 (RNE); element a in low half
__device__ __forceinline__ unsigned pk2(float a, float b) {
    unsigned ua = __float_as_uint(a);
    unsigned ub = __float_as_uint(b);
    ua += 0x7FFFu + ((ua >> 16) & 1u);
    ub += 0x7FFFu + ((ub >> 16) & 1u);
    return (ua >> 16) | (ub & 0xFFFF0000u);
}
__device__ __forceinline__ float blo(unsigned u) { return __uint_as_float(u << 16); }
__device__ __forceinline__ float bhi(unsigned u) { return __uint_as_float(u & 0xFFFF0000u); }
// element f (bf16 element index) from packed array
__device__ __forceinline__ float bfh(const unsigned* E, int f) {
    unsigned w = E[f >> 1];
    return (f & 1) ? bhi(w) : blo(w);
}

// ---------- 1. CSR build: LDS histogram + scan, one block ----------
__global__ __launch_bounds__(1024) void csr_build(const int* __restrict__ ei,
                                                  int* __restrict__ off, int* __restrict__ cur)
{
    __shared__ int hist[NN];       // 32 KB
    __shared__ int wsum[16];
    const int t = threadIdx.x;
    for (int i = t; i < NN; i += 1024) hist[i] = 0;
    __syncthreads();
    for (int i = t; i < NE; i += 1024) atomicAdd(&hist[ei[NE + i]], 1);
    __syncthreads();

    const int base = t * 8;
    int v[8]; int sum = 0;
    #pragma unroll
    for (int j = 0; j < 8; ++j) {
        v[j] = (base + j < NN) ? hist[base + j] : 0;
        sum += v[j];
    }
    const int lane = t & 63, w = t >> 6;   // 16 waves
    int x = sum;
    #pragma unroll
    for (int d = 1; d < 64; d <<= 1) {
        int y = __shfl_up(x, d);
        if (lane >= d) x += y;
    }
    if (lane == 63) wsum[w] = x;
    __syncthreads();
    if (t < 64) {
        int y = (t < 16) ? wsum[t] : 0;
        #pragma unroll
        for (int d = 1; d < 16; d <<= 1) {
            int z = __shfl_up(y, d);
            if (lane >= d) y += z;
        }
        if (t < 16) wsum[t] = y;
    }
    __syncthreads();
    int excl = ((w > 0) ? wsum[w - 1] : 0) + (x - sum);
    #pragma unroll
    for (int j = 0; j < 8; ++j) {
        if (base + j < NN) { off[base + j] = excl; cur[base + j] = excl; }
        excl += v[j];
    }
    if (t == 0) off[NN] = NE;
}

// ---------- 2. fused CSR-fill + per-edge basis (e-coalesced inputs, slot-ordered outputs) ----------
__global__ __launch_bounds__(256) void fill_basis(
    const float* __restrict__ pos, const int* __restrict__ atnum,
    const int* __restrict__ ei, const float* __restrict__ shifts,
    const float* __restrict__ embW, const float* __restrict__ radW,
    int* __restrict__ cur,
    unsigned* __restrict__ edat, int* __restrict__ slist, float* __restrict__ fclist)
{
    const int e = blockIdx.x * blockDim.x + threadIdx.x;
    if (e >= NE) return;
    const int s = ei[e];
    const int r = ei[NE + e];
    const int slot = atomicAdd(&cur[r], 1);   // issue early; result needed only at the end

    const float dx = pos[r*3+0] - pos[s*3+0] + shifts[e*3+0];
    const float dy = pos[r*3+1] - pos[s*3+1] + shifts[e*3+1];
    const float dz = pos[r*3+2] - pos[s*3+2] + shifts[e*3+2];
    const float len = sqrtf(dx*dx + dy*dy + dz*dz);
    const float inv = 1.f / (len + EPSV);
    const float ux = dx*inv, uy = dy*inv, uz = dz*inv;

    const float u  = len / CUT;
    const float u2 = u*u;
    const float u6 = u2*u2*u2;
    const float fcut = (u < 1.f) ? (1.f - 28.f*u6 + 48.f*u6*u - 21.f*u6*u2) : 0.f;

    float E[56];

    // rad[k] = sqrt(2/CUT)*sin((k+1)*pi*len/CUT)/len via sin recurrence
    float rad[NR];
    {
        const float th = len * (float)(M_PI / (double)CUT);
        float sc, cc;
        sincosf(th, &sc, &cc);
        const float cr = sqrtf(2.f/CUT) * inv;
        const float c2 = 2.f * cc;
        float skm1 = 0.f, sk = sc;
        #pragma unroll
        for (int k = 0; k < NR; ++k) {
            rad[k] = cr * sk;
            const float nx = c2 * sk - skm1;
            skm1 = sk; sk = nx;
        }
    }

    #pragma unroll
    for (int l = 0; l < 4; ++l)
        #pragma unroll
        for (int p = 0; p < NP; ++p) {
            float acc = 0.f;
            #pragma unroll
            for (int rr = 0; rr < NR; ++rr) acc += rad[rr] * radW[l*NR*NP + rr*NP + p];
            E[l*NP + p] = fcut * acc;
        }

    {
        float px[4] = {1.f, ux, ux*ux, ux*ux*ux};
        float py[4] = {1.f, uy, uy*uy, uy*uy*uy};
        float pz[4] = {1.f, uz, uz*uz, uz*uz*uz};
        #pragma unroll
        for (int a = 0; a < NA; ++a)
            E[24 + a] = px[c_lx[a]] * py[c_ly[a]] * pz[c_lz[a]];
    }
    {
        const int ss = spec_of(atnum[s]), sr = spec_of(atnum[r]);
        #pragma unroll
        for (int c = 0; c < NC; ++c)
            E[44 + c] = embW[ss*3 + c/3] * embW[sr*3 + c%3];
    }
    E[53] = 0.f; E[54] = 0.f; E[55] = 0.f;

    unsigned P[EDW];
    #pragma unroll
    for (int f = 0; f < EDW; ++f) P[f] = pk2(E[2*f], E[2*f+1]);

    slist[slot]  = s;
    fclist[slot] = fcut;
    uint4* __restrict__ E4 = (uint4*)(edat + (size_t)slot * EDW);
    #pragma unroll
    for (int f = 0; f < 7; ++f)
        E4[f] = make_uint4(P[4*f], P[4*f+1], P[4*f+2], P[4*f+3]);
}

// ---------- 3. node-centric A0 accumulation: CONTIGUOUS slot stream -> bf16 row ----------
__global__ __launch_bounds__(128) void node_accum(
    const unsigned* __restrict__ edat, const int* __restrict__ off,
    unsigned short* __restrict__ A0h)
{
    const int n = blockIdx.x;
    const int tid = threadIdx.x;
    // 120 active threads: tid = p*NA + a
    const bool act = (tid < NP * NA);
    const int p = tid / NA, a = tid % NA;
    const int l = (a >= 1) + (a >= 4) + (a >= 10);
    const int iR = l*NP + p;

    float acc[NC];
    #pragma unroll
    for (int c = 0; c < NC; ++c) acc[c] = 0.f;

    __shared__ uint4 sE4[EB * 7];
    const unsigned* sE = (const unsigned*)sE4;
    __shared__ __align__(16) float sRow[PAC];

    const int st = off[n], en = off[n+1];
    const uint4* __restrict__ gbase = (const uint4*)edat;
    for (int i0 = st; i0 < en; i0 += EB) {
        const int nb = min(EB, en - i0);
        __syncthreads();
        for (int q = tid; q < nb * 7; q += 128)
            sE4[q] = gbase[(size_t)i0 * 7 + q];
        __syncthreads();
        if (act) {
            for (int b = 0; b < nb; ++b) {
                const unsigned* E = &sE[b * EDW];
                const float ra = bfh(E, iR) * bfh(E, 24 + a);
                #pragma unroll
                for (int c = 0; c < NC; ++c) acc[c] = fmaf(ra, bfh(E, 44 + c), acc[c]);
            }
        }
    }
    if (act) {
        #pragma unroll
        for (int c = 0; c < NC; ++c) sRow[tid * NC + c] = acc[c];
    }
    __syncthreads();

    // pack 1080 floats -> 270 uint2 chunks
    uint2* __restrict__ row = (uint2*)(A0h + (size_t)n * PAC);
    #pragma unroll
    for (int k = 0; k < 3; ++k) {
        const int q = tid + 128 * k;
        if (q < 270) {
            const float* s4 = &sRow[4 * q];
            row[q] = make_uint2(pk2(s4[0], s4[1]), pk2(s4[2], s4[3]));
        }
    }
}

// ---------- 4. fused MP gather (bf16, uint4) + symmetrize + output ----------
__global__ __launch_bounds__(MPT) void node_mp_final(
    const unsigned short* __restrict__ A0h,
    const int* __restrict__ slist, const float* __restrict__ fclist,
    const int* __restrict__ off, const float* __restrict__ memc,
    float* __restrict__ out)
{
    const int n = blockIdx.x;
    const int tid = threadIdx.x;

    __shared__ int   sS[MPT];
    __shared__ float sF[MPT];
    __shared__ __align__(16) float sA[2 * PAC];   // [0,1080): A0_n  [1080,2160): A1_n
    __shared__ __align__(16) float sOut[544];

    const int st = off[n], en = off[n+1];
    const bool gact = (tid < 135);                // uint4 chunk ids (135 per row)
    float a0=0,a1=0,a2=0,a3=0,a4=0,a5=0,a6=0,a7=0;

    for (int b0 = st; b0 < en; b0 += MPT) {
        const int nb = min(MPT, en - b0);
        __syncthreads();
        if (tid < nb) { sS[tid] = slist[b0 + tid]; sF[tid] = fclist[b0 + tid]; }
        __syncthreads();
        int j = 0;
        for (; j + 8 <= nb; j += 8) {
            if (gact) {
                uint4 v[8];
                #pragma unroll
                for (int k = 0; k < 8; ++k)
                    v[k] = ((const uint4*)(A0h + (size_t)sS[j+k] * PAC))[tid];
                #pragma unroll
                for (int k = 0; k < 8; ++k) {
                    const float f = sF[j+k];
                    a0 = fmaf(f, blo(v[k].x), a0);
                    a1 = fmaf(f, bhi(v[k].x), a1);
                    a2 = fmaf(f, blo(v[k].y), a2);
                    a3 = fmaf(f, bhi(v[k].y), a3);
                    a4 = fmaf(f, blo(v[k].z), a4);
                    a5 = fmaf(f, bhi(v[k].z), a5);
                    a6 = fmaf(f, blo(v[k].w), a6);
                    a7 = fmaf(f, bhi(v[k].w), a7);
                }
            }
        }
        for (; j < nb; ++j) {
            if (gact) {
                const float f = sF[j];
                uint4 v = ((const uint4*)(A0h + (size_t)sS[j] * PAC))[tid];
                a0 = fmaf(f, blo(v.x), a0);
                a1 = fmaf(f, bhi(v.x), a1);
                a2 = fmaf(f, blo(v.y), a2);
                a3 = fmaf(f, bhi(v.y), a3);
                a4 = fmaf(f, blo(v.z), a4);
                a5 = fmaf(f, bhi(v.z), a5);
                a6 = fmaf(f, blo(v.w), a6);
                a7 = fmaf(f, bhi(v.w), a7);
            }
        }
    }

    const float mc  = memc[0];
    const float mpn = 0.3162277660168379f;  // 1/sqrt(10)
    if (gact) {
        uint4 v = ((const uint4*)(A0h + (size_t)n * PAC))[tid];
        const float x0 = blo(v.x), x1 = bhi(v.x), x2 = blo(v.y), x3 = bhi(v.y);
        const float x4 = blo(v.z), x5 = bhi(v.z), x6 = blo(v.w), x7 = bhi(v.w);
        float4* sA4  = (float4*)sA;
        float4* sA14 = (float4*)(sA + PAC);
        sA4[2*tid]     = make_float4(x0, x1, x2, x3);
        sA4[2*tid + 1] = make_float4(x4, x5, x6, x7);
        sA14[2*tid]     = make_float4(fmaf(mc, x0, mpn*a0), fmaf(mc, x1, mpn*a1),
                                      fmaf(mc, x2, mpn*a2), fmaf(mc, x3, mpn*a3));
        sA14[2*tid + 1] = make_float4(fmaf(mc, x4, mpn*a4), fmaf(mc, x5, mpn*a5),
                                      fmaf(mc, x6, mpn*a6), fmaf(mc, x7, mpn*a7));
    }
    __syncthreads();

    if (tid < NP * NC) {
        const int p = tid / NC, c = tid % NC;
        const int base = p * (NA * NC) + c;
        float b20[4] = {0.f,0.f,0.f,0.f};
        float b21[4] = {0.f,0.f,0.f,0.f};
        #pragma unroll
        for (int a = 0; a < NA; ++a) {
            const int ll = c_ls[a];
            const float pr = c_pref[a];
            const float x0 = sA[base + a*NC];
            const float x1 = sA[PAC + base + a*NC];
            b20[ll] = fmaf(pr * x0, x0, b20[ll]);
            b21[ll] = fmaf(pr * x1, x1, b21[ll]);
        }
        const int ob = p*90 + c*2;
        sOut[ob]     = sA[base];
        sOut[ob + 1] = sA[PAC + base];
        #pragma unroll
        for (int ll = 0; ll < 4; ++ll) {
            sOut[ob + (ll+1)*18]     = b20[ll];
            sOut[ob + (ll+1)*18 + 1] = b21[ll];
        }
    }
    __syncthreads();

    float4* __restrict__ o4 = (float4*)(out + (size_t)n * 540);
    if (tid < 135) o4[tid] = ((const float4*)sOut)[tid];
}

extern "C" void kernel_launch(void* const* d_in, const int* in_sizes, int n_in,
                              void* d_out, int out_size, void* d_ws, size_t ws_size,
                              hipStream_t stream) {
    const float* pos    = (const float*)d_in[0];
    const int*   atnum  = (const int*)d_in[1];
    const int*   ei     = (const int*)d_in[2];
    const float* shifts = (const float*)d_in[3];
    const float* embW   = (const float*)d_in[4];
    const float* radW   = (const float*)d_in[5];
    const float* memc   = (const float*)d_in[6];
    float* out = (float*)d_out;

    unsigned*       edat = (unsigned*)d_ws;                    // NE*28 uints (8.96 MB)
    unsigned short* A0h  = (unsigned short*)(edat + (size_t)NE * EDW);  // NN*1080 bf16 (17.28 MB)
    float* fclist = (float*)(A0h + (size_t)NN * PAC);          // NE
    int*   off    = (int*)(fclist + NE);                       // NN+1
    int*   cur    = off + NN + 1;                              // NN
    int*   slist  = cur + NN;                                  // NE

    csr_build<<<1, 1024, 0, stream>>>(ei, off, cur);
    fill_basis<<<(NE+255)/256, 256, 0, stream>>>(pos, atnum, ei, shifts, embW, radW,
                                                 cur, edat, slist, fclist);
    node_accum<<<NN, 128, 0, stream>>>(edat, off, A0h);
    node_mp_final<<<NN, MPT, 0, stream>>>(A0h, slist, fclist, off, memc, out);
}

// Round 11
// 90.805 us; speedup vs baseline: 1.1947x; 1.0418x over previous
//
#include <hip/hip_runtime.h>
#include <math.h>

#define NN 8000
#define NE 80000
#define NP 6
#define NR 6
#define NA 20
#define NC 9
#define PAC (NP*NA*NC)   // 1080
#define TW  360          // T row: [p][a][i], 6*20*3
#define EDW 24           // per-slot packed row: 48 bf16 = 24 uints (96 B)
#define CUT 5.5f
#define EPSV 1e-9f
#define EB 16            // edges per LDS stage in node_accum

__constant__ int   c_lx[NA]  = {0, 1,0,0, 2,1,1,0,0,0, 3,2,2,1,1,1,0,0,0,0};
__constant__ int   c_ly[NA]  = {0, 0,1,0, 0,1,0,2,1,0, 0,1,0,2,1,0,3,2,1,0};
__constant__ int   c_lz[NA]  = {0, 0,0,1, 0,0,1,0,1,2, 0,0,1,0,1,2,0,1,2,3};
__constant__ int   c_ls[NA]  = {0, 1,1,1, 2,2,2,2,2,2, 3,3,3,3,3,3,3,3,3,3};
__constant__ float c_pref[NA]= {1.f, 1.f,1.f,1.f, 1.f,2.f,2.f,1.f,2.f,1.f,
                                1.f,3.f,3.f,3.f,6.f,3.f,1.f,3.f,3.f,1.f};

__device__ __forceinline__ int spec_of(int z) { return z == 1 ? 0 : (z == 6 ? 1 : 2); }

// pack two f32 -> one uint of 2 bf16 (RNE); element a in low half
__device__ __forceinline__ unsigned pk2(float a, float b) {
    unsigned ua = __float_as_uint(a);
    unsigned ub = __float_as_uint(b);
    ua += 0x7FFFu + ((ua >> 16) & 1u);
    ub += 0x7FFFu + ((ub >> 16) & 1u);
    return (ua >> 16) | (ub & 0xFFFF0000u);
}
__device__ __forceinline__ float blo(unsigned u) { return __uint_as_float(u << 16); }
__device__ __forceinline__ float bhi(unsigned u) { return __uint_as_float(u & 0xFFFF0000u); }
__device__ __forceinline__ float bfh(const unsigned* E, int f) {
    unsigned w = E[f >> 1];
    return (f & 1) ? bhi(w) : blo(w);
}

// ---------- 1. CSR build: LDS histogram + scan, one block ----------
__global__ __launch_bounds__(1024) void csr_build(const int* __restrict__ ei,
                                                  int* __restrict__ off, int* __restrict__ cur)
{
    __shared__ int hist[NN];       // 32 KB
    __shared__ int wsum[16];
    const int t = threadIdx.x;
    for (int i = t; i < NN; i += 1024) hist[i] = 0;
    __syncthreads();
    for (int i = t; i < NE; i += 1024) atomicAdd(&hist[ei[NE + i]], 1);
    __syncthreads();

    const int base = t * 8;
    int v[8]; int sum = 0;
    #pragma unroll
    for (int j = 0; j < 8; ++j) {
        v[j] = (base + j < NN) ? hist[base + j] : 0;
        sum += v[j];
    }
    const int lane = t & 63, w = t >> 6;   // 16 waves
    int x = sum;
    #pragma unroll
    for (int d = 1; d < 64; d <<= 1) {
        int y = __shfl_up(x, d);
        if (lane >= d) x += y;
    }
    if (lane == 63) wsum[w] = x;
    __syncthreads();
    if (t < 64) {
        int y = (t < 16) ? wsum[t] : 0;
        #pragma unroll
        for (int d = 1; d < 16; d <<= 1) {
            int z = __shfl_up(y, d);
            if (lane >= d) y += z;
        }
        if (t < 16) wsum[t] = y;
    }
    __syncthreads();
    int excl = ((w > 0) ? wsum[w - 1] : 0) + (x - sum);
    #pragma unroll
    for (int j = 0; j < 8; ++j) {
        if (base + j < NN) { off[base + j] = excl; cur[base + j] = excl; }
        excl += v[j];
    }
    if (t == 0) off[NN] = NE;
}

// ---------- 2. fused CSR-fill + per-edge basis (e-coalesced in, slot-ordered out) ----------
__global__ __launch_bounds__(256) void fill_basis(
    const float* __restrict__ pos, const int* __restrict__ atnum,
    const int* __restrict__ ei, const float* __restrict__ shifts,
    const float* __restrict__ embW, const float* __restrict__ radW,
    int* __restrict__ cur,
    unsigned* __restrict__ edat, int* __restrict__ slist, float* __restrict__ fclist)
{
    const int e = blockIdx.x * blockDim.x + threadIdx.x;
    if (e >= NE) return;
    const int s = ei[e];
    const int r = ei[NE + e];
    const int slot = atomicAdd(&cur[r], 1);

    const float dx = pos[r*3+0] - pos[s*3+0] + shifts[e*3+0];
    const float dy = pos[r*3+1] - pos[s*3+1] + shifts[e*3+1];
    const float dz = pos[r*3+2] - pos[s*3+2] + shifts[e*3+2];
    const float len = sqrtf(dx*dx + dy*dy + dz*dz);
    const float inv = 1.f / (len + EPSV);
    const float ux = dx*inv, uy = dy*inv, uz = dz*inv;

    const float u  = len / CUT;
    const float u2 = u*u;
    const float u6 = u2*u2*u2;
    const float fcut = (u < 1.f) ? (1.f - 28.f*u6 + 48.f*u6*u - 21.f*u6*u2) : 0.f;

    float E[48];

    float rad[NR];
    {
        const float th = len * (float)(M_PI / (double)CUT);
        float sc, cc;
        sincosf(th, &sc, &cc);
        const float cr = sqrtf(2.f/CUT) * inv;
        const float c2 = 2.f * cc;
        float skm1 = 0.f, sk = sc;
        #pragma unroll
        for (int k = 0; k < NR; ++k) {
            rad[k] = cr * sk;
            const float nx = c2 * sk - skm1;
            skm1 = sk; sk = nx;
        }
    }

    #pragma unroll
    for (int l = 0; l < 4; ++l)
        #pragma unroll
        for (int p = 0; p < NP; ++p) {
            float acc = 0.f;
            #pragma unroll
            for (int rr = 0; rr < NR; ++rr) acc += rad[rr] * radW[l*NR*NP + rr*NP + p];
            E[l*NP + p] = fcut * acc;
        }

    {
        float px[4] = {1.f, ux, ux*ux, ux*ux*ux};
        float py[4] = {1.f, uy, uy*uy, uy*uy*uy};
        float pz[4] = {1.f, uz, uz*uz, uz*uz*uz};
        #pragma unroll
        for (int a = 0; a < NA; ++a)
            E[24 + a] = px[c_lx[a]] * py[c_ly[a]] * pz[c_lz[a]];
    }
    const int ss = spec_of(atnum[s]);
    E[44] = embW[ss*3+0]; E[45] = embW[ss*3+1]; E[46] = embW[ss*3+2];
    E[47] = 0.f;

    unsigned P[EDW];
    #pragma unroll
    for (int f = 0; f < EDW; ++f) P[f] = pk2(E[2*f], E[2*f+1]);

    slist[slot]  = s | (ss << 16);
    fclist[slot] = fcut;
    uint4* __restrict__ E4 = (uint4*)(edat + (size_t)slot * EDW);
    #pragma unroll
    for (int f = 0; f < 6; ++f)
        E4[f] = make_uint4(P[4*f], P[4*f+1], P[4*f+2], P[4*f+3]);
}

// ---------- 3. node-centric T accumulation: contiguous slot stream -> bf16 T row ----------
__global__ __launch_bounds__(128) void node_accum(
    const unsigned* __restrict__ edat, const int* __restrict__ off,
    unsigned short* __restrict__ Th)
{
    const int n = blockIdx.x;
    const int tid = threadIdx.x;
    const bool act = (tid < NP * NA);     // 120 threads: tid = p*NA + a
    const int p = tid / NA, a = tid % NA;
    const int l = (a >= 1) + (a >= 4) + (a >= 10);
    const int iR = l*NP + p;

    float acc0 = 0.f, acc1 = 0.f, acc2 = 0.f;

    __shared__ uint4 sE4[EB * 6];
    const unsigned* sE = (const unsigned*)sE4;
    __shared__ __align__(16) float sRow[TW];

    const int st = off[n], en = off[n+1];
    const uint4* __restrict__ gbase = (const uint4*)edat;
    for (int i0 = st; i0 < en; i0 += EB) {
        const int nb = min(EB, en - i0);
        __syncthreads();
        for (int q = tid; q < nb * 6; q += 128)
            sE4[q] = gbase[(size_t)i0 * 6 + q];
        __syncthreads();
        if (act) {
            for (int b = 0; b < nb; ++b) {
                const unsigned* E = &sE[b * EDW];
                const float ra = bfh(E, iR) * bfh(E, 24 + a);
                acc0 = fmaf(ra, bfh(E, 44), acc0);
                acc1 = fmaf(ra, bfh(E, 45), acc1);
                acc2 = fmaf(ra, bfh(E, 46), acc2);
            }
        }
    }
    if (act) {
        sRow[tid*3 + 0] = acc0;
        sRow[tid*3 + 1] = acc1;
        sRow[tid*3 + 2] = acc2;
    }
    __syncthreads();

    // pack 360 floats -> 45 uint4 (8 bf16 each)
    uint4* __restrict__ row = (uint4*)(Th + (size_t)n * TW);
    if (tid < 45) {
        const float* s8 = &sRow[8 * tid];
        row[tid] = make_uint4(pk2(s8[0], s8[1]), pk2(s8[2], s8[3]),
                              pk2(s8[4], s8[5]), pk2(s8[6], s8[7]));
    }
}

// ---------- 4. fused MP gather (bf16 T, species-bucketed) + reconstruct + symmetrize ----------
__global__ __launch_bounds__(128) void node_mp_final(
    const unsigned short* __restrict__ Th,
    const int* __restrict__ atnum,
    const int* __restrict__ slist, const float* __restrict__ fclist,
    const int* __restrict__ off, const float* __restrict__ embW,
    const float* __restrict__ memc, float* __restrict__ out)
{
    const int n = blockIdx.x;
    const int tid = threadIdx.x;

    __shared__ int   sS[128];
    __shared__ float sF[128];
    __shared__ __align__(16) float sT[TW];
    __shared__ __align__(16) float sB[3][TW];
    __shared__ __align__(16) float sA[2 * PAC];   // A0_n | A1_n
    __shared__ __align__(16) float sOut[544];

    const int st = off[n], en = off[n+1];
    const bool gact = (tid < 90);                 // uint2 chunks of T row (90 * 4 bf16)
    float4 bA = {0,0,0,0}, bB = {0,0,0,0}, bC = {0,0,0,0};

    for (int b0 = st; b0 < en; b0 += 128) {
        const int nb = min(128, en - b0);
        __syncthreads();
        if (tid < nb) { sS[tid] = slist[b0 + tid]; sF[tid] = fclist[b0 + tid]; }
        __syncthreads();
        if (gact) {
            for (int j = 0; j < nb; ++j) {
                const int pj = sS[j];
                const float fj = sF[j];
                const uint2 v = ((const uint2*)(Th + (size_t)(pj & 0xFFFF) * TW))[tid];
                const float e0 = blo(v.x), e1 = bhi(v.x), e2 = blo(v.y), e3 = bhi(v.y);
                const int kk = pj >> 16;          // block-uniform species tag
                if (kk == 0) {
                    bA.x = fmaf(fj, e0, bA.x); bA.y = fmaf(fj, e1, bA.y);
                    bA.z = fmaf(fj, e2, bA.z); bA.w = fmaf(fj, e3, bA.w);
                } else if (kk == 1) {
                    bB.x = fmaf(fj, e0, bB.x); bB.y = fmaf(fj, e1, bB.y);
                    bB.z = fmaf(fj, e2, bB.z); bB.w = fmaf(fj, e3, bB.w);
                } else {
                    bC.x = fmaf(fj, e0, bC.x); bC.y = fmaf(fj, e1, bC.y);
                    bC.z = fmaf(fj, e2, bC.z); bC.w = fmaf(fj, e3, bC.w);
                }
            }
        }
    }

    if (gact) {
        uint2 tv = ((const uint2*)(Th + (size_t)n * TW))[tid];
        const int q = 4 * tid;
        sT[q+0] = blo(tv.x); sT[q+1] = bhi(tv.x);
        sT[q+2] = blo(tv.y); sT[q+3] = bhi(tv.y);
        ((float4*)&sB[0][q])[0] = bA;
        ((float4*)&sB[1][q])[0] = bB;
        ((float4*)&sB[2][q])[0] = bC;
    }
    __syncthreads();

    const float mc  = memc[0];
    const float mpn = 0.3162277660168379f;  // 1/sqrt(10)
    if (tid < NP * NA) {                    // 120 threads: pa
        const int sr = spec_of(atnum[n]);
        const float enj[3] = {embW[sr*3+0], embW[sr*3+1], embW[sr*3+2]};
        const int q = tid * 3;
        #pragma unroll
        for (int i = 0; i < 3; ++i) {
            const float ti = sT[q + i];
            const float b0 = sB[0][q + i], b1 = sB[1][q + i], b2 = sB[2][q + i];
            #pragma unroll
            for (int j = 0; j < 3; ++j) {
                const float a0v = ti * enj[j];
                const float agg = embW[0*3+j]*b0 + embW[1*3+j]*b1 + embW[2*3+j]*b2;
                sA[tid*NC + i*3 + j]        = a0v;
                sA[PAC + tid*NC + i*3 + j]  = fmaf(mc, a0v, mpn * agg);
            }
        }
    }
    __syncthreads();

    if (tid < NP * NC) {
        const int p = tid / NC, c = tid % NC;
        const int base = p * (NA * NC) + c;
        float b20[4] = {0.f,0.f,0.f,0.f};
        float b21[4] = {0.f,0.f,0.f,0.f};
        #pragma unroll
        for (int a = 0; a < NA; ++a) {
            const int ll = c_ls[a];
            const float pr = c_pref[a];
            const float x0 = sA[base + a*NC];
            const float x1 = sA[PAC + base + a*NC];
            b20[ll] = fmaf(pr * x0, x0, b20[ll]);
            b21[ll] = fmaf(pr * x1, x1, b21[ll]);
        }
        const int ob = p*90 + c*2;
        sOut[ob]     = sA[base];
        sOut[ob + 1] = sA[PAC + base];
        #pragma unroll
        for (int ll = 0; ll < 4; ++ll) {
            sOut[ob + (ll+1)*18]     = b20[ll];
            sOut[ob + (ll+1)*18 + 1] = b21[ll];
        }
    }
    __syncthreads();

    // 540 floats = 135 float4 chunks; 128 threads -> grid-stride (R9 bug: tail was dropped)
    float4* __restrict__ o4 = (float4*)(out + (size_t)n * 540);
    for (int q = tid; q < 135; q += 128)
        o4[q] = ((const float4*)sOut)[q];
}

extern "C" void kernel_launch(void* const* d_in, const int* in_sizes, int n_in,
                              void* d_out, int out_size, void* d_ws, size_t ws_size,
                              hipStream_t stream) {
    const float* pos    = (const float*)d_in[0];
    const int*   atnum  = (const int*)d_in[1];
    const int*   ei     = (const int*)d_in[2];
    const float* shifts = (const float*)d_in[3];
    const float* embW   = (const float*)d_in[4];
    const float* radW   = (const float*)d_in[5];
    const float* memc   = (const float*)d_in[6];
    float* out = (float*)d_out;

    unsigned*       edat = (unsigned*)d_ws;                    // NE*24 uints (7.68 MB)
    unsigned short* Th   = (unsigned short*)(edat + (size_t)NE * EDW);  // NN*360 bf16 (5.76 MB)
    float* fclist = (float*)(Th + (size_t)NN * TW);            // NE
    int*   off    = (int*)(fclist + NE);                       // NN+1
    int*   cur    = off + NN + 1;                              // NN
    int*   slist  = cur + NN;                                  // NE

    csr_build<<<1, 1024, 0, stream>>>(ei, off, cur);
    fill_basis<<<(NE+255)/256, 256, 0, stream>>>(pos, atnum, ei, shifts, embW, radW,
                                                 cur, edat, slist, fclist);
    node_accum<<<NN, 128, 0, stream>>>(edat, off, Th);
    node_mp_final<<<NN, 128, 0, stream>>>(Th, atnum, slist, fclist, off, embW, memc, out);
}